// Round 8
// baseline (385.397 us; speedup 1.0000x reference)
//
#include <hip/hip_runtime.h>

// Flash attention, non-causal: O = softmax(Q K^T / sqrt(64)) V
// B=64, S=2048, D=64, fp32 in/out, bf16 MFMA compute (fp32 accum).
//
// R8: LDS-pipe relief. After R7's XCD swizzle, K is L2-resident, so the
// K-tile LDS round-trip (stage write + 8 b128 frag reads/wave-iter) buys
// nothing: build K fragments DIRECTLY from global (lane (r,qh) loads
// K[kt+16t+r][32c+8qh..+8], two dwordx4 L2 hits, no barrier dep).
// Removes ~40% of LDS-pipe traffic + the K bank conflicts. V keeps LDS
// (transpose); P round-trip + sacc ones-mfma + (64,16) grid kept.

typedef short bf16x8 __attribute__((ext_vector_type(8)));
typedef float f32x4 __attribute__((ext_vector_type(4)));

#define SQK 0.18033688011112042f /* (1/8) * log2(e) : softmax in exp2 domain */

__device__ __forceinline__ short f2bf(float x) {
  unsigned u = __float_as_uint(x);
  u = (u + 0x7fffu + ((u >> 16) & 1u)) >> 16;  // RNE (one-time Q conv only)
  return (short)u;
}

// pack two floats to bf16x2 (round-half-up): 2 adds + 1 v_perm
__device__ __forceinline__ unsigned pk2(float lo, float hi) {
  unsigned a = __float_as_uint(lo) + 0x8000u;
  unsigned b = __float_as_uint(hi) + 0x8000u;
  return __builtin_amdgcn_perm(b, a, 0x07060302u);  // {hi16(b), hi16(a)}
}

union BF8U { unsigned u[4]; bf16x8 f; };

__global__ __launch_bounds__(256) void DotProductAttention_44573170598739_kernel(
    const float* __restrict__ Q, const float* __restrict__ K,
    const float* __restrict__ V, float* __restrict__ O) {
  constexpr int S = 2048, D = 64;
  const int b   = blockIdx.x;                // batch (XCD-locality swizzle)
  const int q0  = blockIdx.y * 128;          // block's first q row
  const int tid = threadIdx.x;
  const int w    = tid >> 6;                 // wave 0..3
  const int lane = tid & 63;
  const int qh   = lane >> 4;                // quad 0..3
  const int r    = lane & 15;

  __shared__ __align__(16) short vsh[64 * 72];      // V tile, transposed [d][key]
  __shared__ __align__(16) short psh[4][32 * 72];   // per-wave P, BOTH strips

  // ---- Q fragments (regs, whole kernel), pre-scaled into exp2 domain.
  bf16x8 qf[2][2];
#pragma unroll
  for (int s = 0; s < 2; ++s)
#pragma unroll
    for (int c = 0; c < 2; ++c) {
      const float* qp = Q + ((size_t)b * S + q0 + w * 32 + s * 16 + r) * D + c * 32 + qh * 8;
      float4 x = ((const float4*)qp)[0];
      float4 y = ((const float4*)qp)[1];
      bf16x8 f;
      f[0] = f2bf(x.x * SQK); f[1] = f2bf(x.y * SQK);
      f[2] = f2bf(x.z * SQK); f[3] = f2bf(x.w * SQK);
      f[4] = f2bf(y.x * SQK); f[5] = f2bf(y.y * SQK);
      f[6] = f2bf(y.z * SQK); f[7] = f2bf(y.w * SQK);
      qf[s][c] = f;
    }

  // all-ones B fragment for row-sum mfma
  bf16x8 onesf;
#pragma unroll
  for (int i = 0; i < 8; ++i) onesf[i] = (short)0x3F80;

  f32x4 oacc[2][4] = {};      // [strip][d-tile], C-layout (row=q, col=d)
  f32x4 sacc[2] = {};         // row sums: sacc[s][g] = sum for q = 4qh+g

  for (int kt = 0; kt < S; kt += 64) {
    // ---- stage V transposed: lane owns column d=lane, wave w owns keys
    //      [w*16, w*16+16). Global: 16 coalesced dword loads.
    const float* Vg = V + ((size_t)b * S + kt) * D;
    float vv[16];
#pragma unroll
    for (int j = 0; j < 16; ++j)
      vv[j] = Vg[(w * 16 + j) * D + lane];
#pragma unroll
    for (int jj = 0; jj < 4; ++jj) {
      uint2 pk = { pk2(vv[4 * jj + 0], vv[4 * jj + 1]),
                   pk2(vv[4 * jj + 2], vv[4 * jj + 3]) };
      *(uint2*)&vsh[lane * 72 + w * 16 + 4 * jj] = pk;
    }
    __syncthreads();

    // ---- K fragments DIRECT from global (L2-resident after R7 swizzle):
    //      lane (r,qh) reads K[kt+16t+r][32c+8qh .. +8] = two dwordx4.
    const float* Kg = K + ((size_t)b * S + kt) * D;
    bf16x8 kf[4][2], vf[4][2];
#pragma unroll
    for (int t = 0; t < 4; ++t)
#pragma unroll
      for (int c = 0; c < 2; ++c) {
        const float* kp = Kg + (16 * t + r) * D + 32 * c + 8 * qh;
        float4 x = ((const float4*)kp)[0];
        float4 y = ((const float4*)kp)[1];
        BF8U z;
        z.u[0] = pk2(x.x, x.y); z.u[1] = pk2(x.z, x.w);
        z.u[2] = pk2(y.x, y.y); z.u[3] = pk2(y.z, y.w);
        kf[t][c] = z.f;
      }
#pragma unroll
    for (int t = 0; t < 4; ++t)
#pragma unroll
      for (int c = 0; c < 2; ++c)
        vf[t][c] = *(const bf16x8*)&vsh[(t * 16 + r) * 72 + c * 32 + qh * 8];

    // ---- both strips: S^T = K Q^T, exp2, P-write. No drain in between.
#pragma unroll
    for (int s = 0; s < 2; ++s) {
      f32x4 sc[4];
#pragma unroll
      for (int t = 0; t < 4; ++t) {
        f32x4 z = {};
        z = __builtin_amdgcn_mfma_f32_16x16x32_bf16(kf[t][0], qf[s][0], z, 0, 0, 0);
        z = __builtin_amdgcn_mfma_f32_16x16x32_bf16(kf[t][1], qf[s][1], z, 0, 0, 0);
        sc[t] = z;
      }
#pragma unroll
      for (int t = 0; t < 4; ++t)
#pragma unroll
        for (int g = 0; g < 4; ++g)
          sc[t][g] = __builtin_amdgcn_exp2f(sc[t][g]);
#pragma unroll
      for (int t = 0; t < 4; ++t) {
        uint2 pk = { pk2(sc[t][0], sc[t][1]), pk2(sc[t][2], sc[t][3]) };
        *(uint2*)&psh[w][(s * 16 + r) * 72 + t * 16 + 4 * qh] = pk;
      }
    }

    // ---- single drain, then PV (+ row-sum mfma) for both strips
    __asm__ volatile("s_waitcnt lgkmcnt(0)" ::: "memory");
#pragma unroll
    for (int s = 0; s < 2; ++s)
#pragma unroll
      for (int c = 0; c < 2; ++c) {
        bf16x8 pf = *(const bf16x8*)&psh[w][(s * 16 + r) * 72 + c * 32 + qh * 8];
        sacc[s] = __builtin_amdgcn_mfma_f32_16x16x32_bf16(pf, onesf, sacc[s], 0, 0, 0);
#pragma unroll
        for (int dt = 0; dt < 4; ++dt)
          oacc[s][dt] = __builtin_amdgcn_mfma_f32_16x16x32_bf16(pf, vf[dt][c], oacc[s][dt], 0, 0, 0);
      }
    __syncthreads();
  }

  // ---- epilogue: sacc[s][g] is the row sum for q = 4qh+g (every lane)
#pragma unroll
  for (int s = 0; s < 2; ++s)
#pragma unroll
    for (int g = 0; g < 4; ++g) {
      float inv = 1.0f / sacc[s][g];
      int q = q0 + w * 32 + s * 16 + 4 * qh + g;
      float* op = O + ((size_t)b * S + q) * D + r;
#pragma unroll
      for (int dt = 0; dt < 4; ++dt)
        op[dt * 16] = oacc[s][dt][g] * inv;
    }
}

extern "C" void kernel_launch(void* const* d_in, const int* in_sizes, int n_in,
                              void* d_out, int out_size, void* d_ws, size_t ws_size,
                              hipStream_t stream) {
  (void)in_sizes; (void)n_in; (void)out_size; (void)d_ws; (void)ws_size;
  const float* Q = (const float*)d_in[0];
  const float* K = (const float*)d_in[1];
  const float* V = (const float*)d_in[2];
  float* O = (float*)d_out;
  // grid.x = batch so all q-tile blocks of a batch share an XCD (L2 reuse)
  dim3 grid(64, 2048 / 128, 1);
  dim3 block(256, 1, 1);
  hipLaunchKernelGGL(DotProductAttention_44573170598739_kernel,
                     grid, block, 0, stream, Q, K, V, O);
}

// Round 9
// 228.935 us; speedup vs baseline: 1.6834x; 1.6834x over previous
//
#include <hip/hip_runtime.h>

// Flash attention, non-causal: O = softmax(Q K^T / sqrt(64)) V
// B=64, S=2048, D=64, fp32 in/out, bf16 MFMA compute (fp32 accum).
//
// R9 = R7 (best, 160us) + V register-prefetch across the barrier.
// R8 (direct-global K frags) regressed 2x: scattered L2 reads with no
// latency cover + 4x L2 amplification. Reverted. Here the 16 V staging
// loads for tile i+1 issue in phase B (right after frag reads) and are
// held in regs across the end-of-loop barrier; phase A just packs+writes.
// The compiler's vmcnt(0)-before-s_barrier guarantees arrival; 2-barrier
// single-buffer structure (R7) is kept so there is no R6-style race.
// VGPR ~124 keeps 4 waves/SIMD (>128 would cost a block/CU).

typedef short bf16x8 __attribute__((ext_vector_type(8)));
typedef float f32x4 __attribute__((ext_vector_type(4)));

#define SQK 0.18033688011112042f /* (1/8) * log2(e) : softmax in exp2 domain */

__device__ __forceinline__ short f2bf(float x) {
  unsigned u = __float_as_uint(x);
  u = (u + 0x7fffu + ((u >> 16) & 1u)) >> 16;  // RNE (one-time Q conv only)
  return (short)u;
}

// pack two floats to bf16x2 (round-half-up): 2 adds + 1 v_perm
__device__ __forceinline__ unsigned pk2(float lo, float hi) {
  unsigned a = __float_as_uint(lo) + 0x8000u;
  unsigned b = __float_as_uint(hi) + 0x8000u;
  return __builtin_amdgcn_perm(b, a, 0x07060302u);  // {hi16(b), hi16(a)}
}

__global__ __launch_bounds__(256) void DotProductAttention_44573170598739_kernel(
    const float* __restrict__ Q, const float* __restrict__ K,
    const float* __restrict__ V, float* __restrict__ O) {
  constexpr int S = 2048, D = 64;
  const int b   = blockIdx.x;                // batch (XCD-locality swizzle)
  const int q0  = blockIdx.y * 128;          // block's first q row
  const int tid = threadIdx.x;
  const int w    = tid >> 6;                 // wave 0..3
  const int lane = tid & 63;
  const int qh   = lane >> 4;                // quad 0..3
  const int r    = lane & 15;

  __shared__ __align__(16) short ksh[64 * 72];      // K tile, row-major [key][d]
  __shared__ __align__(16) short vsh[64 * 72];      // V tile, transposed [d][key]
  __shared__ __align__(16) short psh[4][32 * 72];   // per-wave P, BOTH strips

  // ---- Q fragments (regs, whole kernel), pre-scaled into exp2 domain.
  bf16x8 qf[2][2];
#pragma unroll
  for (int s = 0; s < 2; ++s)
#pragma unroll
    for (int c = 0; c < 2; ++c) {
      const float* qp = Q + ((size_t)b * S + q0 + w * 32 + s * 16 + r) * D + c * 32 + qh * 8;
      float4 x = ((const float4*)qp)[0];
      float4 y = ((const float4*)qp)[1];
      bf16x8 f;
      f[0] = f2bf(x.x * SQK); f[1] = f2bf(x.y * SQK);
      f[2] = f2bf(x.z * SQK); f[3] = f2bf(x.w * SQK);
      f[4] = f2bf(y.x * SQK); f[5] = f2bf(y.y * SQK);
      f[6] = f2bf(y.z * SQK); f[7] = f2bf(y.w * SQK);
      qf[s][c] = f;
    }

  // all-ones B fragment for row-sum mfma
  bf16x8 onesf;
#pragma unroll
  for (int i = 0; i < 8; ++i) onesf[i] = (short)0x3F80;

  f32x4 oacc[2][4] = {};      // [strip][d-tile], C-layout (row=q, col=d)
  f32x4 sacc[2] = {};         // row sums: sacc[s][g] = sum for q = 4qh+g

  const float* Kb = K + (size_t)b * S * D;
  const float* Vb = V + (size_t)b * S * D;

  // ---- prologue: V tile 0 into prefetch regs (lane owns column d=lane,
  //      wave w owns keys [w*16, w*16+16); 16 coalesced dword loads)
  float vv[16];
#pragma unroll
  for (int j = 0; j < 16; ++j)
    vv[j] = Vb[(w * 16 + j) * D + lane];

  for (int kt = 0; kt < S; kt += 64) {
    // ---- phase A: stage K (load+pack+write) and V (pack+write from regs)
    const float* Kg = Kb + (size_t)kt * D;
#pragma unroll
    for (int i = 0; i < 4; ++i) {
      float4 x = ((const float4*)Kg)[tid + 256 * i];
      int f = 4 * tid + 1024 * i;
      int row = f >> 6, col = f & 63;
      uint2 pk = { pk2(x.x, x.y), pk2(x.z, x.w) };
      *(uint2*)&ksh[row * 72 + col] = pk;
    }
#pragma unroll
    for (int jj = 0; jj < 4; ++jj) {
      uint2 pk = { pk2(vv[4 * jj + 0], vv[4 * jj + 1]),
                   pk2(vv[4 * jj + 2], vv[4 * jj + 3]) };
      *(uint2*)&vsh[lane * 72 + w * 16 + 4 * jj] = pk;
    }
    __syncthreads();

    // ---- phase B: fragment reads, then immediately issue next V loads
    bf16x8 kf[4][2], vf[4][2];
#pragma unroll
    for (int t = 0; t < 4; ++t)
#pragma unroll
      for (int c = 0; c < 2; ++c) {
        kf[t][c] = *(const bf16x8*)&ksh[(t * 16 + r) * 72 + c * 32 + qh * 8];
        vf[t][c] = *(const bf16x8*)&vsh[(t * 16 + r) * 72 + c * 32 + qh * 8];
      }

    // prefetch V tile kt+64 (clamped; last-iter value unused). Latency
    // rides across the whole compute phase; vmcnt(0) before the loop-end
    // barrier guarantees arrival before next phase A consumes the regs.
    {
      const int kt2 = (kt + 64 < S) ? kt + 64 : 0;
      const float* Vg2 = Vb + (size_t)kt2 * D;
#pragma unroll
      for (int j = 0; j < 16; ++j)
        vv[j] = Vg2[(w * 16 + j) * D + lane];
    }

    // ---- both strips: S^T = K Q^T, exp2, P-write. No drain in between.
#pragma unroll
    for (int s = 0; s < 2; ++s) {
      f32x4 sc[4];
#pragma unroll
      for (int t = 0; t < 4; ++t) {
        f32x4 z = {};
        z = __builtin_amdgcn_mfma_f32_16x16x32_bf16(kf[t][0], qf[s][0], z, 0, 0, 0);
        z = __builtin_amdgcn_mfma_f32_16x16x32_bf16(kf[t][1], qf[s][1], z, 0, 0, 0);
        sc[t] = z;
      }
#pragma unroll
      for (int t = 0; t < 4; ++t)
#pragma unroll
        for (int g = 0; g < 4; ++g)
          sc[t][g] = __builtin_amdgcn_exp2f(sc[t][g]);
#pragma unroll
      for (int t = 0; t < 4; ++t) {
        uint2 pk = { pk2(sc[t][0], sc[t][1]), pk2(sc[t][2], sc[t][3]) };
        *(uint2*)&psh[w][(s * 16 + r) * 72 + t * 16 + 4 * qh] = pk;
      }
    }

    // ---- single drain, then PV (+ row-sum mfma) for both strips
    __asm__ volatile("s_waitcnt lgkmcnt(0)" ::: "memory");
#pragma unroll
    for (int s = 0; s < 2; ++s)
#pragma unroll
      for (int c = 0; c < 2; ++c) {
        bf16x8 pf = *(const bf16x8*)&psh[w][(s * 16 + r) * 72 + c * 32 + qh * 8];
        sacc[s] = __builtin_amdgcn_mfma_f32_16x16x32_bf16(pf, onesf, sacc[s], 0, 0, 0);
#pragma unroll
        for (int dt = 0; dt < 4; ++dt)
          oacc[s][dt] = __builtin_amdgcn_mfma_f32_16x16x32_bf16(pf, vf[dt][c], oacc[s][dt], 0, 0, 0);
      }
    __syncthreads();
  }

  // ---- epilogue: sacc[s][g] is the row sum for q = 4qh+g (every lane)
#pragma unroll
  for (int s = 0; s < 2; ++s)
#pragma unroll
    for (int g = 0; g < 4; ++g) {
      float inv = 1.0f / sacc[s][g];
      int q = q0 + w * 32 + s * 16 + 4 * qh + g;
      float* op = O + ((size_t)b * S + q) * D + r;
#pragma unroll
      for (int dt = 0; dt < 4; ++dt)
        op[dt * 16] = oacc[s][dt][g] * inv;
    }
}

extern "C" void kernel_launch(void* const* d_in, const int* in_sizes, int n_in,
                              void* d_out, int out_size, void* d_ws, size_t ws_size,
                              hipStream_t stream) {
  (void)in_sizes; (void)n_in; (void)out_size; (void)d_ws; (void)ws_size;
  const float* Q = (const float*)d_in[0];
  const float* K = (const float*)d_in[1];
  const float* V = (const float*)d_in[2];
  float* O = (float*)d_out;
  // grid.x = batch so all q-tile blocks of a batch share an XCD (L2 reuse)
  dim3 grid(64, 2048 / 128, 1);
  dim3 block(256, 1, 1);
  hipLaunchKernelGGL(DotProductAttention_44573170598739_kernel,
                     grid, block, 0, stream, Q, K, V, O);
}

// Round 10
// 223.882 us; speedup vs baseline: 1.7214x; 1.0226x over previous
//
#include <hip/hip_runtime.h>

// Flash attention, non-causal: O = softmax(Q K^T / sqrt(64)) V
// B=64, S=2048, D=64, fp32 in/out, bf16 MFMA compute (fp32 accum).
//
// R10 = R9 (145us) + K register-prefetch (symmetric to R9's proven V
// prefetch). Phase A is now pure pack+write from regs -- zero global
// waits between the loop-end barrier and the staging writes. Both K and
// V tiles for kt+64 are issued in phase B right after the fragment
// reads; vmcnt(0)-before-s_barrier guarantees arrival. VGPR ~120 keeps
// 4 waves/SIMD. Conflicts (1.47e7) now understood as structural
// ds_read_b128 overhead (~4-5 cy/instr, m134) -- not chased further.

typedef short bf16x8 __attribute__((ext_vector_type(8)));
typedef float f32x4 __attribute__((ext_vector_type(4)));

#define SQK 0.18033688011112042f /* (1/8) * log2(e) : softmax in exp2 domain */

__device__ __forceinline__ short f2bf(float x) {
  unsigned u = __float_as_uint(x);
  u = (u + 0x7fffu + ((u >> 16) & 1u)) >> 16;  // RNE (one-time Q conv only)
  return (short)u;
}

// pack two floats to bf16x2 (round-half-up): 2 adds + 1 v_perm
__device__ __forceinline__ unsigned pk2(float lo, float hi) {
  unsigned a = __float_as_uint(lo) + 0x8000u;
  unsigned b = __float_as_uint(hi) + 0x8000u;
  return __builtin_amdgcn_perm(b, a, 0x07060302u);  // {hi16(b), hi16(a)}
}

__global__ __launch_bounds__(256) void DotProductAttention_44573170598739_kernel(
    const float* __restrict__ Q, const float* __restrict__ K,
    const float* __restrict__ V, float* __restrict__ O) {
  constexpr int S = 2048, D = 64;
  const int b   = blockIdx.x;                // batch (XCD-locality swizzle)
  const int q0  = blockIdx.y * 128;          // block's first q row
  const int tid = threadIdx.x;
  const int w    = tid >> 6;                 // wave 0..3
  const int lane = tid & 63;
  const int qh   = lane >> 4;                // quad 0..3
  const int r    = lane & 15;

  __shared__ __align__(16) short ksh[64 * 72];      // K tile, row-major [key][d]
  __shared__ __align__(16) short vsh[64 * 72];      // V tile, transposed [d][key]
  __shared__ __align__(16) short psh[4][32 * 72];   // per-wave P, BOTH strips

  // ---- Q fragments (regs, whole kernel), pre-scaled into exp2 domain.
  bf16x8 qf[2][2];
#pragma unroll
  for (int s = 0; s < 2; ++s)
#pragma unroll
    for (int c = 0; c < 2; ++c) {
      const float* qp = Q + ((size_t)b * S + q0 + w * 32 + s * 16 + r) * D + c * 32 + qh * 8;
      float4 x = ((const float4*)qp)[0];
      float4 y = ((const float4*)qp)[1];
      bf16x8 f;
      f[0] = f2bf(x.x * SQK); f[1] = f2bf(x.y * SQK);
      f[2] = f2bf(x.z * SQK); f[3] = f2bf(x.w * SQK);
      f[4] = f2bf(y.x * SQK); f[5] = f2bf(y.y * SQK);
      f[6] = f2bf(y.z * SQK); f[7] = f2bf(y.w * SQK);
      qf[s][c] = f;
    }

  // all-ones B fragment for row-sum mfma
  bf16x8 onesf;
#pragma unroll
  for (int i = 0; i < 8; ++i) onesf[i] = (short)0x3F80;

  f32x4 oacc[2][4] = {};      // [strip][d-tile], C-layout (row=q, col=d)
  f32x4 sacc[2] = {};         // row sums: sacc[s][g] = sum for q = 4qh+g

  const float* Kb = K + (size_t)b * S * D;
  const float* Vb = V + (size_t)b * S * D;

  // ---- prologue: K and V tile 0 into prefetch regs
  float4 kx[4];
  float  vv[16];
#pragma unroll
  for (int i = 0; i < 4; ++i)
    kx[i] = ((const float4*)Kb)[tid + 256 * i];
#pragma unroll
  for (int j = 0; j < 16; ++j)
    vv[j] = Vb[(w * 16 + j) * D + lane];

  for (int kt = 0; kt < S; kt += 64) {
    // ---- phase A: pack+write K and V tiles from prefetch regs (no waits)
#pragma unroll
    for (int i = 0; i < 4; ++i) {
      int f = 4 * tid + 1024 * i;
      int row = f >> 6, col = f & 63;
      uint2 pk = { pk2(kx[i].x, kx[i].y), pk2(kx[i].z, kx[i].w) };
      *(uint2*)&ksh[row * 72 + col] = pk;
    }
#pragma unroll
    for (int jj = 0; jj < 4; ++jj) {
      uint2 pk = { pk2(vv[4 * jj + 0], vv[4 * jj + 1]),
                   pk2(vv[4 * jj + 2], vv[4 * jj + 3]) };
      *(uint2*)&vsh[lane * 72 + w * 16 + 4 * jj] = pk;
    }
    __syncthreads();

    // ---- phase B: fragment reads, then immediately issue next K/V loads
    bf16x8 kf[4][2], vf[4][2];
#pragma unroll
    for (int t = 0; t < 4; ++t)
#pragma unroll
      for (int c = 0; c < 2; ++c) {
        kf[t][c] = *(const bf16x8*)&ksh[(t * 16 + r) * 72 + c * 32 + qh * 8];
        vf[t][c] = *(const bf16x8*)&vsh[(t * 16 + r) * 72 + c * 32 + qh * 8];
      }

    // prefetch K/V tile kt+64 (clamped; last-iter values unused). Latency
    // rides across the whole compute phase; vmcnt(0) before the loop-end
    // barrier guarantees arrival before next phase A consumes the regs.
    {
      const int kt2 = (kt + 64 < S) ? kt + 64 : 0;
      const float* Kg2 = Kb + (size_t)kt2 * D;
      const float* Vg2 = Vb + (size_t)kt2 * D;
#pragma unroll
      for (int i = 0; i < 4; ++i)
        kx[i] = ((const float4*)Kg2)[tid + 256 * i];
#pragma unroll
      for (int j = 0; j < 16; ++j)
        vv[j] = Vg2[(w * 16 + j) * D + lane];
    }

    // ---- both strips: S^T = K Q^T, exp2, P-write. No drain in between.
#pragma unroll
    for (int s = 0; s < 2; ++s) {
      f32x4 sc[4];
#pragma unroll
      for (int t = 0; t < 4; ++t) {
        f32x4 z = {};
        z = __builtin_amdgcn_mfma_f32_16x16x32_bf16(kf[t][0], qf[s][0], z, 0, 0, 0);
        z = __builtin_amdgcn_mfma_f32_16x16x32_bf16(kf[t][1], qf[s][1], z, 0, 0, 0);
        sc[t] = z;
      }
#pragma unroll
      for (int t = 0; t < 4; ++t)
#pragma unroll
        for (int g = 0; g < 4; ++g)
          sc[t][g] = __builtin_amdgcn_exp2f(sc[t][g]);
#pragma unroll
      for (int t = 0; t < 4; ++t) {
        uint2 pk = { pk2(sc[t][0], sc[t][1]), pk2(sc[t][2], sc[t][3]) };
        *(uint2*)&psh[w][(s * 16 + r) * 72 + t * 16 + 4 * qh] = pk;
      }
    }

    // ---- single drain, then PV (+ row-sum mfma) for both strips
    __asm__ volatile("s_waitcnt lgkmcnt(0)" ::: "memory");
#pragma unroll
    for (int s = 0; s < 2; ++s)
#pragma unroll
      for (int c = 0; c < 2; ++c) {
        bf16x8 pf = *(const bf16x8*)&psh[w][(s * 16 + r) * 72 + c * 32 + qh * 8];
        sacc[s] = __builtin_amdgcn_mfma_f32_16x16x32_bf16(pf, onesf, sacc[s], 0, 0, 0);
#pragma unroll
        for (int dt = 0; dt < 4; ++dt)
          oacc[s][dt] = __builtin_amdgcn_mfma_f32_16x16x32_bf16(pf, vf[dt][c], oacc[s][dt], 0, 0, 0);
      }
    __syncthreads();
  }

  // ---- epilogue: sacc[s][g] is the row sum for q = 4qh+g (every lane)
#pragma unroll
  for (int s = 0; s < 2; ++s)
#pragma unroll
    for (int g = 0; g < 4; ++g) {
      float inv = 1.0f / sacc[s][g];
      int q = q0 + w * 32 + s * 16 + 4 * qh + g;
      float* op = O + ((size_t)b * S + q) * D + r;
#pragma unroll
      for (int dt = 0; dt < 4; ++dt)
        op[dt * 16] = oacc[s][dt][g] * inv;
    }
}

extern "C" void kernel_launch(void* const* d_in, const int* in_sizes, int n_in,
                              void* d_out, int out_size, void* d_ws, size_t ws_size,
                              hipStream_t stream) {
  (void)in_sizes; (void)n_in; (void)out_size; (void)d_ws; (void)ws_size;
  const float* Q = (const float*)d_in[0];
  const float* K = (const float*)d_in[1];
  const float* V = (const float*)d_in[2];
  float* O = (float*)d_out;
  // grid.x = batch so all q-tile blocks of a batch share an XCD (L2 reuse)
  dim3 grid(64, 2048 / 128, 1);
  dim3 block(256, 1, 1);
  hipLaunchKernelGGL(DotProductAttention_44573170598739_kernel,
                     grid, block, 0, stream, Q, K, V, O);
}